// Round 1
// baseline (564.664 us; speedup 1.0000x reference)
//
#include <hip/hip_runtime.h>
#include <hip/hip_bf16.h>
#include <stdint.h>

#define QLEN 1024
#define MLEN 1024
#define KLEN 2048
#define BSZ 4
#define NH 16
#define DH 64
#define DM 1024

typedef __attribute__((ext_vector_type(8))) short bf16x8;
typedef __attribute__((ext_vector_type(4))) float f32x4;
typedef unsigned short u16;
typedef unsigned int u32;

typedef unsigned int __attribute__((address_space(1))) gu32;
typedef unsigned int __attribute__((address_space(3))) lu32;

__device__ __forceinline__ void stage16(const void* g, void* l){
  __builtin_amdgcn_global_load_lds((const gu32*)g, (lu32*)l, 16, 0, 0);
}

__device__ __forceinline__ u16 f2b(float f){
  u32 u = __builtin_bit_cast(u32, f);
  u32 r = (u + 0x7FFFu + ((u >> 16) & 1u)) >> 16;
  return (u16)r;
}
__device__ __forceinline__ float b2f(u16 v){
  u32 u = ((u32)v) << 16;
  return __builtin_bit_cast(float, u);
}

// ---------------- conversion kernels ----------------

__global__ __launch_bounds__(256) void conv_cat(const float* __restrict__ mems,
                                                const float* __restrict__ w,
                                                u16* __restrict__ dst){
  int idx = blockIdx.x * 256 + threadIdx.x;            // float4 index, total 2097152
  const int memf4 = MLEN * BSZ * DM / 4;               // 1048576
  float4 v = (idx < memf4) ? ((const float4*)mems)[idx]
                           : ((const float4*)w)[idx - memf4];
  ushort4 o;
  o.x = f2b(v.x); o.y = f2b(v.y); o.z = f2b(v.z); o.w = f2b(v.w);
  ((ushort4*)dst)[idx] = o;
}

__global__ __launch_bounds__(256) void conv_r(const float* __restrict__ r,
                                              u16* __restrict__ dst){
  int idx = blockIdx.x * 256 + threadIdx.x;            // total 524288
  float4 v = ((const float4*)r)[idx];
  ushort4 o;
  o.x = f2b(v.x); o.y = f2b(v.y); o.z = f2b(v.z); o.w = f2b(v.w);
  ((ushort4*)dst)[idx] = o;
}

// transpose+convert: src [R][C] f32 -> dst [C][R] bf16
__global__ __launch_bounds__(256) void transpose_conv(const float* __restrict__ src,
                                                      u16* __restrict__ dst,
                                                      int R, int C){
  __shared__ float tile[32][33];
  int c0 = blockIdx.x * 32, r0 = blockIdx.y * 32;
  int tx = threadIdx.x & 31, ty = threadIdx.x >> 5;   // ty in [0,8)
  #pragma unroll
  for (int rr = ty; rr < 32; rr += 8)
    tile[rr][tx] = src[(size_t)(r0 + rr) * C + c0 + tx];
  __syncthreads();
  #pragma unroll
  for (int rr = ty; rr < 32; rr += 8)
    dst[(size_t)(c0 + rr) * R + r0 + tx] = f2b(tile[tx][rr]);
}

// ---------------- generic bf16 MFMA GEMM (128x128 tile, BK=32) ----------------
// A: [M][K] bf16 row-major, Bt: [N][K] bf16 row-major (i.e. B transposed).
// MODE 0: QKV projection epilogue (writes qw,qr,k,v with biases)
// MODE 1: R projection epilogue (writes rh in [h][t][d])
// MODE 2: G = (q+rrb) @ rh^T per (b,h) with shear-at-write
// MODE 3: plain f32 row-major C

template<int MODE>
__global__ __launch_bounds__(256, 2) void gemm_k(
    const u16* __restrict__ A, const u16* __restrict__ Bt, int K,
    void* __restrict__ o0, void* __restrict__ o1, void* __restrict__ o2, void* __restrict__ o3,
    const float* __restrict__ f0, const float* __restrict__ f1, int bIdx)
{
  __shared__ u16 As[128 * 32];
  __shared__ u16 Bs[128 * 32];
  const int tid = threadIdx.x;
  const int lane = tid & 63, w = tid >> 6;
  const int wr = w >> 1, wc = w & 1;
  const int lr = lane >> 4, lc = lane & 15;
  const int m0 = blockIdx.y * 128, n0 = blockIdx.x * 128;

  if (MODE == 2 && (m0 + n0 < 769)) return;   // fully-masked G block (j<0 everywhere)

  const u16* Ab = A;
  const u16* Bb = Bt;
  if (MODE == 2){
    Ab = A + (size_t)(bIdx * NH + blockIdx.z) * QLEN * DH;
    Bb = Bt + (size_t)blockIdx.z * KLEN * DH;
  }

  f32x4 acc[4][4];
  #pragma unroll
  for (int i = 0; i < 4; i++)
    #pragma unroll
    for (int j = 0; j < 4; j++)
      acc[i][j] = (f32x4){0.f, 0.f, 0.f, 0.f};

  for (int k0 = 0; k0 < K; k0 += 32){
    #pragma unroll
    for (int rnd = 0; rnd < 2; rnd++){
      int c = rnd * 256 + w * 64 + lane;
      int row = c >> 2, kc = c & 3;
      stage16((const char*)Ab + ((size_t)(m0 + row) * K + k0 + kc * 8) * 2,
              (char*)As + (rnd * 256 + w * 64) * 16);
      stage16((const char*)Bb + ((size_t)(n0 + row) * K + k0 + kc * 8) * 2,
              (char*)Bs + (rnd * 256 + w * 64) * 16);
    }
    asm volatile("s_waitcnt vmcnt(0)");
    __syncthreads();

    bf16x8 af[4], bfr[4];
    #pragma unroll
    for (int mf = 0; mf < 4; mf++)
      af[mf] = *(const bf16x8*)((const char*)As + (wr * 64 + mf * 16 + lc) * 64 + lr * 16);
    #pragma unroll
    for (int nf = 0; nf < 4; nf++)
      bfr[nf] = *(const bf16x8*)((const char*)Bs + (wc * 64 + nf * 16 + lc) * 64 + lr * 16);
    #pragma unroll
    for (int mf = 0; mf < 4; mf++)
      #pragma unroll
      for (int nf = 0; nf < 4; nf++)
        acc[mf][nf] = __builtin_amdgcn_mfma_f32_16x16x32_bf16(af[mf], bfr[nf], acc[mf][nf], 0, 0, 0);
    __syncthreads();
  }

  #pragma unroll
  for (int mf = 0; mf < 4; mf++){
    #pragma unroll
    for (int nf = 0; nf < 4; nf++){
      #pragma unroll
      for (int e = 0; e < 4; e++){
        float v = acc[mf][nf][e];
        int row = m0 + wr * 64 + mf * 16 + lr * 4 + e;
        int col = n0 + wc * 64 + nf * 16 + lc;
        if constexpr (MODE == 0){
          int t = row >> 2, bb = row & 3;
          int s = col >> 10, rem = col & 1023;
          int h = rem >> 6, d = rem & 63;
          if (s == 0){
            if (t >= MLEN){
              size_t oi = ((size_t)(bb * NH + h) * QLEN + (t - MLEN)) * DH + d;
              ((u16*)o0)[oi] = f2b(v + f0[rem]);   // q + r_w_bias
              ((u16*)o1)[oi] = f2b(v + f1[rem]);   // q + r_r_bias
            }
          } else {
            size_t oi = ((size_t)(bb * NH + h) * KLEN + t) * DH + d;
            if (s == 1) ((u16*)o2)[oi] = f2b(v);   // k
            else        ((u16*)o3)[oi] = f2b(v);   // v
          }
        } else if constexpr (MODE == 1){
          int h = col >> 6, d = col & 63;
          ((u16*)o0)[((size_t)h * KLEN + row) * DH + d] = f2b(v);
        } else if constexpr (MODE == 2){
          int j = col - (QLEN - 1) + row;          // shear: t -> j
          if (j >= 0)
            ((u16*)o0)[((size_t)blockIdx.z * QLEN + row) * KLEN + j] = f2b(v);
        } else {
          ((float*)o0)[(size_t)row * DM + col] = v;
        }
      }
    }
  }
}

// ---------------- flash attention with precomputed sheared G ----------------
// One block = one (i-tile of 64 rows, head). 4 waves, each wave owns 16 q-rows.

__global__ __launch_bounds__(256, 2) void attn_k(
    const u16* __restrict__ qwB, const u16* __restrict__ kB, const u16* __restrict__ vB,
    const u16* __restrict__ Gs, u16* __restrict__ av, int b)
{
  __shared__ u16 Kt[64 * 64];        // [j][d]
  __shared__ u16 Vt[64 * 64];        // [d][j]  (transposed)
  __shared__ u16 Gt[64 * 64];        // [i-row][j-col] sheared-G tile
  __shared__ u16 Pt[4][16 * 64];     // per-wave P tile [row][j]
  const int tid = threadIdx.x, lane = tid & 63, w = tid >> 6;
  const int lr = lane >> 4, lc = lane & 15;
  const int h = blockIdx.y;
  const int i0 = blockIdx.x * 64;
  const size_t bh = (size_t)b * NH + h;

  // Q fragments (rows i0 + w*16 + lc), already biased with r_w_bias
  bf16x8 qf[2];
  #pragma unroll
  for (int ks = 0; ks < 2; ks++)
    qf[ks] = *(const bf16x8*)(qwB + (bh * QLEN + i0 + w * 16 + lc) * DH + ks * 32 + lr * 8);

  f32x4 O[4];
  float mx[4], sm[4];
  #pragma unroll
  for (int df = 0; df < 4; df++) O[df] = (f32x4){0.f, 0.f, 0.f, 0.f};
  #pragma unroll
  for (int e = 0; e < 4; e++){ mx[e] = -3.0e38f; sm[e] = 0.f; }

  const char* kgb = (const char*)(kB + bh * KLEN * DH);
  const char* vgb = (const char*)(vB + bh * KLEN * DH);
  const char* ggb = (const char*)(Gs + ((size_t)h * QLEN + i0) * KLEN);

  const int jtiles = (i0 >> 6) + 17;   // covers j <= i0+63+MLEN

  for (int jt = 0; jt < jtiles; jt++){
    const int j0 = jt * 64;
    // stage K tile (contiguous 8KB)
    #pragma unroll
    for (int rnd = 0; rnd < 2; rnd++){
      int off = rnd * 256 + w * 64;
      stage16(kgb + (size_t)j0 * 128 + (off + lane) * 16, (char*)Kt + off * 16);
    }
    // stage sheared-G tile (rows strided by KLEN)
    #pragma unroll
    for (int rnd = 0; rnd < 2; rnd++){
      int off = rnd * 256 + w * 64;
      int c = off + lane;
      stage16(ggb + (size_t)(c >> 3) * (KLEN * 2) + j0 * 2 + (c & 7) * 16,
              (char*)Gt + off * 16);
    }
    // stage V transposed via registers
    #pragma unroll
    for (int rnd = 0; rnd < 2; rnd++){
      int c = rnd * 256 + tid;
      bf16x8 vv = *(const bf16x8*)(vgb + (size_t)j0 * 128 + c * 16);
      int j = c >> 3, d0 = (c & 7) * 8;
      #pragma unroll
      for (int e2 = 0; e2 < 8; e2++)
        Vt[(d0 + e2) * 64 + j] = (u16)vv[e2];
    }
    asm volatile("s_waitcnt vmcnt(0)");
    __syncthreads();

    // S = (Q+rwb) K^T  (4 col-fragments)
    f32x4 s[4];
    #pragma unroll
    for (int n = 0; n < 4; n++){
      bf16x8 k0f = *(const bf16x8*)((const char*)Kt + (n * 16 + lc) * 128 + lr * 16);
      bf16x8 k1f = *(const bf16x8*)((const char*)Kt + (n * 16 + lc) * 128 + 64 + lr * 16);
      f32x4 z = (f32x4){0.f, 0.f, 0.f, 0.f};
      z = __builtin_amdgcn_mfma_f32_16x16x32_bf16(qf[0], k0f, z, 0, 0, 0);
      z = __builtin_amdgcn_mfma_f32_16x16x32_bf16(qf[1], k1f, z, 0, 0, 0);
      s[n] = z;
    }

    float p[4][4];   // [n][e]
    float fac[4];
    #pragma unroll
    for (int e = 0; e < 4; e++){
      int rowL = w * 16 + lr * 4 + e;
      int i = i0 + rowL;
      float sv[4];
      float tm = -3.0e38f;
      #pragma unroll
      for (int n = 0; n < 4; n++){
        float x = (s[n][e] + b2f(Gt[rowL * 64 + n * 16 + lc])) * 0.125f;
        int j = j0 + n * 16 + lc;
        if (j > i + MLEN) x = -1.0e30f;
        sv[n] = x;
        tm = fmaxf(tm, x);
      }
      #pragma unroll
      for (int m2 = 1; m2 < 16; m2 <<= 1) tm = fmaxf(tm, __shfl_xor(tm, m2));
      float nm = fmaxf(mx[e], tm);
      float fc = __expf(mx[e] - nm);
      mx[e] = nm;
      float ps = 0.f;
      #pragma unroll
      for (int n = 0; n < 4; n++){
        float pv = __expf(sv[n] - nm);
        p[n][e] = pv;
        ps += pv;
      }
      #pragma unroll
      for (int m2 = 1; m2 < 16; m2 <<= 1) ps += __shfl_xor(ps, m2);
      sm[e] = sm[e] * fc + ps;
      fac[e] = fc;
    }
    #pragma unroll
    for (int df = 0; df < 4; df++)
      #pragma unroll
      for (int e = 0; e < 4; e++)
        O[df][e] *= fac[e];
    #pragma unroll
    for (int n = 0; n < 4; n++)
      #pragma unroll
      for (int e = 0; e < 4; e++)
        Pt[w][(lr * 4 + e) * 64 + n * 16 + lc] = f2b(p[n][e]);

    asm volatile("s_waitcnt lgkmcnt(0)" ::: "memory");

    // O += P @ V
    bf16x8 pa0 = *(const bf16x8*)((const char*)(&Pt[w][0]) + lc * 128 + lr * 16);
    bf16x8 pa1 = *(const bf16x8*)((const char*)(&Pt[w][0]) + lc * 128 + 64 + lr * 16);
    #pragma unroll
    for (int df = 0; df < 4; df++){
      bf16x8 v0 = *(const bf16x8*)((const char*)Vt + (df * 16 + lc) * 128 + lr * 16);
      bf16x8 v1 = *(const bf16x8*)((const char*)Vt + (df * 16 + lc) * 128 + 64 + lr * 16);
      O[df] = __builtin_amdgcn_mfma_f32_16x16x32_bf16(pa0, v0, O[df], 0, 0, 0);
      O[df] = __builtin_amdgcn_mfma_f32_16x16x32_bf16(pa1, v1, O[df], 0, 0, 0);
    }
    __syncthreads();
  }

  #pragma unroll
  for (int df = 0; df < 4; df++)
    #pragma unroll
    for (int e = 0; e < 4; e++){
      int i = i0 + w * 16 + lr * 4 + e;
      av[(size_t)(i * BSZ + b) * DM + h * DH + df * 16 + lc] = f2b(O[df][e] / sm[e]);
    }
}

// ---------------- residual + LayerNorm ----------------

__global__ __launch_bounds__(256) void ln_k(const float* __restrict__ w,
                                            const float* __restrict__ ao,
                                            const float* __restrict__ gam,
                                            const float* __restrict__ bet,
                                            float* __restrict__ out){
  __shared__ float red[8];
  const int rw = blockIdx.x, t = threadIdx.x, lane = t & 63, wv = t >> 6;
  const float* wr_ = w + (size_t)rw * DM;
  const float* ar_ = ao + (size_t)rw * DM;
  float x[4];
  float s = 0.f, ss = 0.f;
  #pragma unroll
  for (int k2 = 0; k2 < 4; k2++){
    int c = t + k2 * 256;
    float xv = wr_[c] + ar_[c];
    x[k2] = xv; s += xv; ss += xv * xv;
  }
  #pragma unroll
  for (int m2 = 1; m2 < 64; m2 <<= 1){ s += __shfl_xor(s, m2); ss += __shfl_xor(ss, m2); }
  if (lane == 0){ red[wv] = s; red[4 + wv] = ss; }
  __syncthreads();
  s  = red[0] + red[1] + red[2] + red[3];
  ss = red[4] + red[5] + red[6] + red[7];
  float mu = s * (1.f / DM);
  float var = ss * (1.f / DM) - mu * mu;
  float rs = rsqrtf(var + 1e-5f);
  #pragma unroll
  for (int k2 = 0; k2 < 4; k2++){
    int c = t + k2 * 256;
    out[(size_t)rw * DM + c] = (x[k2] - mu) * rs * gam[c] + bet[c];
  }
}

// ---------------- launch ----------------

extern "C" void kernel_launch(void* const* d_in, const int* in_sizes, int n_in,
                              void* d_out, int out_size, void* d_ws, size_t ws_size,
                              hipStream_t stream)
{
  (void)in_sizes; (void)n_in; (void)out_size; (void)ws_size;
  const float* w    = (const float*)d_in[0];
  const float* r    = (const float*)d_in[1];
  const float* mems = (const float*)d_in[2];
  const float* Wqkv = (const float*)d_in[3];
  const float* Wr   = (const float*)d_in[4];
  const float* Wo   = (const float*)d_in[5];
  const float* rwb  = (const float*)d_in[6];
  const float* rrb  = (const float*)d_in[7];
  const float* gam  = (const float*)d_in[8];
  const float* bet  = (const float*)d_in[9];
  float* out = (float*)d_out;

  char* ws = (char*)d_ws;
  size_t off = 0;
  auto alloc = [&](size_t n){ char* p = ws + off; off += (n + 255) & ~(size_t)255; return p; };
  u16* catB  = (u16*)alloc((size_t)KLEN * BSZ * DM * 2);       // 16 MB
  u16* rB    = (u16*)alloc((size_t)KLEN * DM * 2);             // 4 MB
  u16* WqkvT = (u16*)alloc((size_t)3 * DM * DM * 2);           // 6 MB
  u16* WrT   = (u16*)alloc((size_t)DM * DM * 2);               // 2 MB
  u16* WoT   = (u16*)alloc((size_t)DM * DM * 2);               // 2 MB
  u16* qwB   = (u16*)alloc((size_t)BSZ * NH * QLEN * DH * 2);  // 8 MB
  u16* qrB   = (u16*)alloc((size_t)BSZ * NH * QLEN * DH * 2);  // 8 MB
  u16* kBp   = (u16*)alloc((size_t)BSZ * NH * KLEN * DH * 2);  // 16 MB
  u16* vBp   = (u16*)alloc((size_t)BSZ * NH * KLEN * DH * 2);  // 16 MB
  u16* rhB   = (u16*)alloc((size_t)NH * KLEN * DH * 2);        // 4 MB
  u16* Gs    = (u16*)alloc((size_t)NH * QLEN * KLEN * 2);      // 64 MB (per-b slab)
  u16* av    = (u16*)alloc((size_t)QLEN * BSZ * DM * 2);       // 8 MB
  float* ao  = (float*)alloc((size_t)QLEN * BSZ * DM * 4);     // 16 MB

  conv_cat<<<dim3(8192), 256, 0, stream>>>(mems, w, catB);
  conv_r<<<dim3(2048), 256, 0, stream>>>(r, rB);
  transpose_conv<<<dim3(96, 32), 256, 0, stream>>>(Wqkv, WqkvT, DM, 3 * DM);
  transpose_conv<<<dim3(32, 32), 256, 0, stream>>>(Wr, WrT, DM, DM);
  transpose_conv<<<dim3(32, 32), 256, 0, stream>>>(Wo, WoT, DM, DM);

  // QKV projection: [8192,1024] x [1024,3072]
  gemm_k<0><<<dim3(24, 64), 256, 0, stream>>>(catB, WqkvT, DM, qwB, qrB, kBp, vBp, rwb, rrb, 0);
  // R projection: [2048,1024] x [1024,1024]
  gemm_k<1><<<dim3(8, 16), 256, 0, stream>>>(rB, WrT, DM, rhB, nullptr, nullptr, nullptr, nullptr, nullptr, 0);

  for (int b = 0; b < BSZ; b++){
    // G = (q+rrb) @ rh^T, sheared write:  [1024,2048] per (b,h)
    gemm_k<2><<<dim3(16, 8, 16), 256, 0, stream>>>(qrB, rhB, DH, Gs, nullptr, nullptr, nullptr, nullptr, nullptr, b);
    attn_k<<<dim3(16, 16), 256, 0, stream>>>(qwB, kBp, vBp, Gs, av, b);
  }

  // output projection: [4096,1024] x [1024,1024]
  gemm_k<3><<<dim3(8, 32), 256, 0, stream>>>(av, WoT, DM, ao, nullptr, nullptr, nullptr, nullptr, nullptr, 0);
  ln_k<<<dim3(4096), 256, 0, stream>>>(w, ao, gam, bet, out);
}

// Round 2
// 355.116 us; speedup vs baseline: 1.5901x; 1.5901x over previous
//
#include <hip/hip_runtime.h>
#include <hip/hip_bf16.h>
#include <stdint.h>

#define QLEN 1024
#define MLEN 1024
#define KLEN 2048
#define BSZ 4
#define NH 16
#define DH 64
#define DM 1024

typedef __attribute__((ext_vector_type(8))) short bf16x8;
typedef __attribute__((ext_vector_type(4))) float f32x4;
typedef unsigned short u16;
typedef unsigned int u32;

typedef unsigned int __attribute__((address_space(1))) gu32;
typedef unsigned int __attribute__((address_space(3))) lu32;

__device__ __forceinline__ void stage16(const void* g, void* l){
  __builtin_amdgcn_global_load_lds((const gu32*)g, (lu32*)l, 16, 0, 0);
}

__device__ __forceinline__ u16 f2b(float f){
  u32 u = __builtin_bit_cast(u32, f);
  u32 r = (u + 0x7FFFu + ((u >> 16) & 1u)) >> 16;
  return (u16)r;
}
__device__ __forceinline__ float b2f(u16 v){
  u32 u = ((u32)v) << 16;
  return __builtin_bit_cast(float, u);
}

// XOR swizzle for [rows][64]bf16 tiles (128B rows): spreads both the
// MFMA-fragment b128 reads (rows vary with lane&15) and the V-transpose
// scatter writes (rows vary with row>>3) across distinct 16B chunks.
__device__ __forceinline__ int swz(int row, int byteoff){
  return (row << 7) + (byteoff ^ (((row ^ (row >> 3)) & 7) << 4));
}

// ---------------- conversion kernels ----------------

__global__ __launch_bounds__(256) void conv_cat(const float* __restrict__ mems,
                                                const float* __restrict__ w,
                                                u16* __restrict__ dst){
  int idx = blockIdx.x * 256 + threadIdx.x;            // float4 index, total 2097152
  const int memf4 = MLEN * BSZ * DM / 4;               // 1048576
  float4 v = (idx < memf4) ? ((const float4*)mems)[idx]
                           : ((const float4*)w)[idx - memf4];
  ushort4 o;
  o.x = f2b(v.x); o.y = f2b(v.y); o.z = f2b(v.z); o.w = f2b(v.w);
  ((ushort4*)dst)[idx] = o;
}

__global__ __launch_bounds__(256) void conv_r(const float* __restrict__ r,
                                              u16* __restrict__ dst){
  int idx = blockIdx.x * 256 + threadIdx.x;            // total 524288
  float4 v = ((const float4*)r)[idx];
  ushort4 o;
  o.x = f2b(v.x); o.y = f2b(v.y); o.z = f2b(v.z); o.w = f2b(v.w);
  ((ushort4*)dst)[idx] = o;
}

// transpose+convert: src [R][C] f32 -> dst [C][R] bf16
__global__ __launch_bounds__(256) void transpose_conv(const float* __restrict__ src,
                                                      u16* __restrict__ dst,
                                                      int R, int C){
  __shared__ float tile[32][33];
  int c0 = blockIdx.x * 32, r0 = blockIdx.y * 32;
  int tx = threadIdx.x & 31, ty = threadIdx.x >> 5;   // ty in [0,8)
  #pragma unroll
  for (int rr = ty; rr < 32; rr += 8)
    tile[rr][tx] = src[(size_t)(r0 + rr) * C + c0 + tx];
  __syncthreads();
  #pragma unroll
  for (int rr = ty; rr < 32; rr += 8)
    dst[(size_t)(c0 + rr) * R + r0 + tx] = f2b(tile[tx][rr]);
}

// ---------------- generic bf16 MFMA GEMM (128x128 tile, BK=32) ----------------
// A: [M][K] bf16 row-major, Bt: [N][K] bf16 row-major (i.e. B transposed).
// MODE 0: QKV projection epilogue (writes qw,qr,k,v with biases)
// MODE 1: R projection epilogue (writes rh in [h][t][d])
// MODE 3: plain f32 row-major C

template<int MODE>
__global__ __launch_bounds__(256, 2) void gemm_k(
    const u16* __restrict__ A, const u16* __restrict__ Bt, int K,
    void* __restrict__ o0, void* __restrict__ o1, void* __restrict__ o2, void* __restrict__ o3,
    const float* __restrict__ f0, const float* __restrict__ f1)
{
  __shared__ u16 As[128 * 32];
  __shared__ u16 Bs[128 * 32];
  const int tid = threadIdx.x;
  const int lane = tid & 63, w = tid >> 6;
  const int wr = w >> 1, wc = w & 1;
  const int lr = lane >> 4, lc = lane & 15;
  const int m0 = blockIdx.y * 128, n0 = blockIdx.x * 128;

  f32x4 acc[4][4];
  #pragma unroll
  for (int i = 0; i < 4; i++)
    #pragma unroll
    for (int j = 0; j < 4; j++)
      acc[i][j] = (f32x4){0.f, 0.f, 0.f, 0.f};

  for (int k0 = 0; k0 < K; k0 += 32){
    #pragma unroll
    for (int rnd = 0; rnd < 2; rnd++){
      int c = rnd * 256 + w * 64 + lane;
      int row = c >> 2, kc = c & 3;
      stage16((const char*)A + ((size_t)(m0 + row) * K + k0 + kc * 8) * 2,
              (char*)As + (rnd * 256 + w * 64) * 16);
      stage16((const char*)Bt + ((size_t)(n0 + row) * K + k0 + kc * 8) * 2,
              (char*)Bs + (rnd * 256 + w * 64) * 16);
    }
    asm volatile("s_waitcnt vmcnt(0)");
    __syncthreads();

    bf16x8 af[4], bfr[4];
    #pragma unroll
    for (int mf = 0; mf < 4; mf++)
      af[mf] = *(const bf16x8*)((const char*)As + (wr * 64 + mf * 16 + lc) * 64 + lr * 16);
    #pragma unroll
    for (int nf = 0; nf < 4; nf++)
      bfr[nf] = *(const bf16x8*)((const char*)Bs + (wc * 64 + nf * 16 + lc) * 64 + lr * 16);
    #pragma unroll
    for (int mf = 0; mf < 4; mf++)
      #pragma unroll
      for (int nf = 0; nf < 4; nf++)
        acc[mf][nf] = __builtin_amdgcn_mfma_f32_16x16x32_bf16(af[mf], bfr[nf], acc[mf][nf], 0, 0, 0);
    __syncthreads();
  }

  #pragma unroll
  for (int mf = 0; mf < 4; mf++){
    #pragma unroll
    for (int nf = 0; nf < 4; nf++){
      #pragma unroll
      for (int e = 0; e < 4; e++){
        float v = acc[mf][nf][e];
        int row = m0 + wr * 64 + mf * 16 + lr * 4 + e;
        int col = n0 + wc * 64 + nf * 16 + lc;
        if constexpr (MODE == 0){
          int t = row >> 2, bb = row & 3;
          int s = col >> 10, rem = col & 1023;
          int h = rem >> 6, d = rem & 63;
          if (s == 0){
            if (t >= MLEN){
              size_t oi = ((size_t)(bb * NH + h) * QLEN + (t - MLEN)) * DH + d;
              ((u16*)o0)[oi] = f2b(v + f0[rem]);   // q + r_w_bias
              ((u16*)o1)[oi] = f2b(v + f1[rem]);   // q + r_r_bias
            }
          } else {
            size_t oi = ((size_t)(bb * NH + h) * KLEN + t) * DH + d;
            if (s == 1) ((u16*)o2)[oi] = f2b(v);   // k
            else        ((u16*)o3)[oi] = f2b(v);   // v
          }
        } else if constexpr (MODE == 1){
          int h = col >> 6, d = col & 63;
          ((u16*)o0)[((size_t)h * KLEN + row) * DH + d] = f2b(v);
        } else {
          ((float*)o0)[(size_t)row * DM + col] = v;
        }
      }
    }
  }
}

// ---------------- fused flash attention with on-the-fly BD band ----------------
// BD[i,j] = qr_i . r_h[1023 + j - i]: per 64x64 tile the r-band [t0,t0+63]
// (t0 = 1023+j0-i0) slides by 64 per j-tile; each band is MFMA'd once and its
// P-strip kept in LDS (two parity buffers), read back sheared in the softmax.
// One block = (64 q-rows, head, batch). 4 waves, each wave owns 16 q-rows.

__global__ __launch_bounds__(256, 2) void attn_k(
    const u16* __restrict__ qwB, const u16* __restrict__ qrB,
    const u16* __restrict__ kB,  const u16* __restrict__ vB,
    const u16* __restrict__ rhB, u16* __restrict__ av)
{
  __shared__ u16 Kt[64 * 64];          // [j][d] swizzled
  __shared__ u16 Vt[64 * 64];          // [d][j] swizzled (transposed)
  __shared__ u16 Rb2[2][64 * 64];      // r band [t'][d] swizzled, parity dbuf
  __shared__ u16 Pt[4][16 * 64];       // per-wave P tile [row][j] swizzled
  __shared__ float Pbd2[4][2][16][68]; // per-wave BD strips, parity dbuf

  const int tid = threadIdx.x, lane = tid & 63, w = tid >> 6;
  const int lr = lane >> 4, lc = lane & 15;
  const int h = blockIdx.y, b = blockIdx.z;
  const int i0 = blockIdx.x * 64;
  const size_t bh = (size_t)b * NH + h;

  // Q fragments (rows i0 + w*16 + lc): qw = q + r_w_bias, qr = q + r_r_bias
  bf16x8 qw_[2], qr_[2];
  #pragma unroll
  for (int ks = 0; ks < 2; ks++){
    qw_[ks] = *(const bf16x8*)(qwB + (bh * QLEN + i0 + w * 16 + lc) * DH + ks * 32 + lr * 8);
    qr_[ks] = *(const bf16x8*)(qrB + (bh * QLEN + i0 + w * 16 + lc) * DH + ks * 32 + lr * 8);
  }

  f32x4 O[4];
  float mx[4], sm[4];
  #pragma unroll
  for (int df = 0; df < 4; df++) O[df] = (f32x4){0.f, 0.f, 0.f, 0.f};
  #pragma unroll
  for (int e = 0; e < 4; e++){ mx[e] = -3.0e38f; sm[e] = 0.f; }

  const char* kgb = (const char*)(kB + bh * KLEN * DH);
  const char* vgb = (const char*)(vB + bh * KLEN * DH);
  const char* rgb = (const char*)(rhB + (size_t)h * KLEN * DH);

  // ---- prologue: band [t0(0)-64, t0(0)-1] into parity-1 buffers ----
  {
    int tb = 959 - i0;
    #pragma unroll
    for (int rnd = 0; rnd < 2; rnd++){
      int c = rnd * 256 + w * 64 + lane;
      int row = c >> 3;
      int t = tb + row; t = t < 0 ? 0 : t;
      int ch = (c & 7) ^ ((row ^ (row >> 3)) & 7);
      stage16(rgb + (size_t)t * 128 + ch * 16, (char*)&Rb2[1][0] + c * 16);
    }
    asm volatile("s_waitcnt vmcnt(0)");
    __syncthreads();
    #pragma unroll
    for (int n2 = 0; n2 < 4; n2++){
      bf16x8 r0 = *(const bf16x8*)((const char*)&Rb2[1][0] + swz(n2 * 16 + lc, lr * 16));
      bf16x8 r1 = *(const bf16x8*)((const char*)&Rb2[1][0] + swz(n2 * 16 + lc, 64 + lr * 16));
      f32x4 z = (f32x4){0.f, 0.f, 0.f, 0.f};
      z = __builtin_amdgcn_mfma_f32_16x16x32_bf16(qr_[0], r0, z, 0, 0, 0);
      z = __builtin_amdgcn_mfma_f32_16x16x32_bf16(qr_[1], r1, z, 0, 0, 0);
      #pragma unroll
      for (int e = 0; e < 4; e++)
        Pbd2[w][1][lr * 4 + e][n2 * 16 + lc] = z[e];
    }
    __syncthreads();
  }

  const int jtiles = (i0 >> 6) + 17;   // covers j <= i0+63+MLEN

  for (int jt = 0; jt < jtiles; jt++){
    const int j0 = jt * 64;
    const int cur = jt & 1;
    const bool lastT = (jt == jtiles - 1);

    // stage K tile (pre-swizzled source -> linear LDS dest)
    #pragma unroll
    for (int rnd = 0; rnd < 2; rnd++){
      int c = rnd * 256 + w * 64 + lane;
      int row = c >> 3;
      int ch = (c & 7) ^ ((row ^ (row >> 3)) & 7);
      stage16(kgb + (size_t)(j0 + row) * 128 + ch * 16, (char*)Kt + c * 16);
    }
    // stage r band [t0, t0+63], t0 = 1023 - i0 + j0
    {
      int tb = 1023 - i0 + j0;
      #pragma unroll
      for (int rnd = 0; rnd < 2; rnd++){
        int c = rnd * 256 + w * 64 + lane;
        int row = c >> 3;
        int t = tb + row; t = t > 2047 ? 2047 : t;
        int ch = (c & 7) ^ ((row ^ (row >> 3)) & 7);
        stage16(rgb + (size_t)t * 128 + ch * 16, (char*)&Rb2[cur][0] + c * 16);
      }
    }
    // stage V transposed via registers (swizzled scatter)
    #pragma unroll
    for (int rnd = 0; rnd < 2; rnd++){
      int c = rnd * 256 + tid;
      bf16x8 vv = *(const bf16x8*)(vgb + (size_t)j0 * 128 + c * 16);
      int j = c >> 3, d0 = (c & 7) * 8;
      #pragma unroll
      for (int e2 = 0; e2 < 8; e2++)
        *(u16*)((char*)Vt + swz(d0 + e2, j * 2)) = (u16)vv[e2];
    }
    asm volatile("s_waitcnt vmcnt(0)");
    __syncthreads();

    // AC = (q+rwb) K^T
    f32x4 s[4];
    #pragma unroll
    for (int n = 0; n < 4; n++){
      bf16x8 k0f = *(const bf16x8*)((const char*)Kt + swz(n * 16 + lc, lr * 16));
      bf16x8 k1f = *(const bf16x8*)((const char*)Kt + swz(n * 16 + lc, 64 + lr * 16));
      f32x4 z = (f32x4){0.f, 0.f, 0.f, 0.f};
      z = __builtin_amdgcn_mfma_f32_16x16x32_bf16(qw_[0], k0f, z, 0, 0, 0);
      z = __builtin_amdgcn_mfma_f32_16x16x32_bf16(qw_[1], k1f, z, 0, 0, 0);
      s[n] = z;
    }

    // BD band: P[r][t-t0] = (q+rrb) . r_h[t]
    #pragma unroll
    for (int n2 = 0; n2 < 4; n2++){
      bf16x8 r0 = *(const bf16x8*)((const char*)&Rb2[cur][0] + swz(n2 * 16 + lc, lr * 16));
      bf16x8 r1 = *(const bf16x8*)((const char*)&Rb2[cur][0] + swz(n2 * 16 + lc, 64 + lr * 16));
      f32x4 z = (f32x4){0.f, 0.f, 0.f, 0.f};
      z = __builtin_amdgcn_mfma_f32_16x16x32_bf16(qr_[0], r0, z, 0, 0, 0);
      z = __builtin_amdgcn_mfma_f32_16x16x32_bf16(qr_[1], r1, z, 0, 0, 0);
      #pragma unroll
      for (int e = 0; e < 4; e++)
        Pbd2[w][cur][lr * 4 + e][n2 * 16 + lc] = z[e];
    }

    // softmax (BD picked up sheared: col = (j-i) mod 64, parity by sign)
    float p[4][4];   // [n][e]
    float fac[4];
    #pragma unroll
    for (int e = 0; e < 4; e++){
      int r = lr * 4 + e;
      int il = w * 16 + r;
      int i = i0 + il;
      float sv[4];
      float tm = -3.0e38f;
      #pragma unroll
      for (int n = 0; n < 4; n++){
        int jl = n * 16 + lc;
        int dd = jl - il;
        const float* pb = &Pbd2[w][dd >= 0 ? cur : (cur ^ 1)][r][0];
        float x = (s[n][e] + pb[dd & 63]) * 0.125f;
        if (lastT && (j0 + jl > i + MLEN)) x = -1.0e30f;
        sv[n] = x;
        tm = fmaxf(tm, x);
      }
      #pragma unroll
      for (int m2 = 1; m2 < 16; m2 <<= 1) tm = fmaxf(tm, __shfl_xor(tm, m2));
      float nm = fmaxf(mx[e], tm);
      float fc = __expf(mx[e] - nm);
      mx[e] = nm;
      float ps = 0.f;
      #pragma unroll
      for (int n = 0; n < 4; n++){
        float pv = __expf(sv[n] - nm);
        p[n][e] = pv;
        ps += pv;
      }
      #pragma unroll
      for (int m2 = 1; m2 < 16; m2 <<= 1) ps += __shfl_xor(ps, m2);
      sm[e] = sm[e] * fc + ps;
      fac[e] = fc;
    }
    #pragma unroll
    for (int df = 0; df < 4; df++)
      #pragma unroll
      for (int e = 0; e < 4; e++)
        O[df][e] *= fac[e];
    #pragma unroll
    for (int n = 0; n < 4; n++)
      #pragma unroll
      for (int e = 0; e < 4; e++)
        *(u16*)((char*)&Pt[w][0] + swz(lr * 4 + e, (n * 16 + lc) * 2)) = f2b(p[n][e]);

    asm volatile("s_waitcnt lgkmcnt(0)" ::: "memory");

    // O += P @ V
    bf16x8 pa0 = *(const bf16x8*)((const char*)&Pt[w][0] + swz(lc, lr * 16));
    bf16x8 pa1 = *(const bf16x8*)((const char*)&Pt[w][0] + swz(lc, 64 + lr * 16));
    #pragma unroll
    for (int df = 0; df < 4; df++){
      bf16x8 v0 = *(const bf16x8*)((const char*)Vt + swz(df * 16 + lc, lr * 16));
      bf16x8 v1 = *(const bf16x8*)((const char*)Vt + swz(df * 16 + lc, 64 + lr * 16));
      O[df] = __builtin_amdgcn_mfma_f32_16x16x32_bf16(pa0, v0, O[df], 0, 0, 0);
      O[df] = __builtin_amdgcn_mfma_f32_16x16x32_bf16(pa1, v1, O[df], 0, 0, 0);
    }
    __syncthreads();
  }

  #pragma unroll
  for (int df = 0; df < 4; df++)
    #pragma unroll
    for (int e = 0; e < 4; e++){
      int i = i0 + w * 16 + lr * 4 + e;
      av[(size_t)(i * BSZ + b) * DM + h * DH + df * 16 + lc] = f2b(O[df][e] / sm[e]);
    }
}

// ---------------- residual + LayerNorm ----------------

__global__ __launch_bounds__(256) void ln_k(const float* __restrict__ w,
                                            const float* __restrict__ ao,
                                            const float* __restrict__ gam,
                                            const float* __restrict__ bet,
                                            float* __restrict__ out){
  __shared__ float red[8];
  const int rw = blockIdx.x, t = threadIdx.x, lane = t & 63, wv = t >> 6;
  const float* wr_ = w + (size_t)rw * DM;
  const float* ar_ = ao + (size_t)rw * DM;
  float x[4];
  float s = 0.f, ss = 0.f;
  #pragma unroll
  for (int k2 = 0; k2 < 4; k2++){
    int c = t + k2 * 256;
    float xv = wr_[c] + ar_[c];
    x[k2] = xv; s += xv; ss += xv * xv;
  }
  #pragma unroll
  for (int m2 = 1; m2 < 64; m2 <<= 1){ s += __shfl_xor(s, m2); ss += __shfl_xor(ss, m2); }
  if (lane == 0){ red[wv] = s; red[4 + wv] = ss; }
  __syncthreads();
  s  = red[0] + red[1] + red[2] + red[3];
  ss = red[4] + red[5] + red[6] + red[7];
  float mu = s * (1.f / DM);
  float var = ss * (1.f / DM) - mu * mu;
  float rs = rsqrtf(var + 1e-5f);
  #pragma unroll
  for (int k2 = 0; k2 < 4; k2++){
    int c = t + k2 * 256;
    out[(size_t)rw * DM + c] = (x[k2] - mu) * rs * gam[c] + bet[c];
  }
}

// ---------------- launch ----------------

extern "C" void kernel_launch(void* const* d_in, const int* in_sizes, int n_in,
                              void* d_out, int out_size, void* d_ws, size_t ws_size,
                              hipStream_t stream)
{
  (void)in_sizes; (void)n_in; (void)out_size; (void)ws_size;
  const float* w    = (const float*)d_in[0];
  const float* r    = (const float*)d_in[1];
  const float* mems = (const float*)d_in[2];
  const float* Wqkv = (const float*)d_in[3];
  const float* Wr   = (const float*)d_in[4];
  const float* Wo   = (const float*)d_in[5];
  const float* rwb  = (const float*)d_in[6];
  const float* rrb  = (const float*)d_in[7];
  const float* gam  = (const float*)d_in[8];
  const float* bet  = (const float*)d_in[9];
  float* out = (float*)d_out;

  char* ws = (char*)d_ws;
  size_t off = 0;
  auto alloc = [&](size_t n){ char* p = ws + off; off += (n + 255) & ~(size_t)255; return p; };
  u16* catB  = (u16*)alloc((size_t)KLEN * BSZ * DM * 2);       // 16 MB
  u16* rB    = (u16*)alloc((size_t)KLEN * DM * 2);             // 4 MB
  u16* WqkvT = (u16*)alloc((size_t)3 * DM * DM * 2);           // 6 MB
  u16* WrT   = (u16*)alloc((size_t)DM * DM * 2);               // 2 MB
  u16* WoT   = (u16*)alloc((size_t)DM * DM * 2);               // 2 MB
  u16* qwB   = (u16*)alloc((size_t)BSZ * NH * QLEN * DH * 2);  // 8 MB
  u16* qrB   = (u16*)alloc((size_t)BSZ * NH * QLEN * DH * 2);  // 8 MB
  u16* kBp   = (u16*)alloc((size_t)BSZ * NH * KLEN * DH * 2);  // 16 MB
  u16* vBp   = (u16*)alloc((size_t)BSZ * NH * KLEN * DH * 2);  // 16 MB
  u16* rhB   = (u16*)alloc((size_t)NH * KLEN * DH * 2);        // 4 MB
  u16* av    = (u16*)alloc((size_t)QLEN * BSZ * DM * 2);       // 8 MB
  float* ao  = (float*)alloc((size_t)QLEN * BSZ * DM * 4);     // 16 MB

  conv_cat<<<dim3(8192), 256, 0, stream>>>(mems, w, catB);
  conv_r<<<dim3(2048), 256, 0, stream>>>(r, rB);
  transpose_conv<<<dim3(96, 32), 256, 0, stream>>>(Wqkv, WqkvT, DM, 3 * DM);
  transpose_conv<<<dim3(32, 32), 256, 0, stream>>>(Wr, WrT, DM, DM);
  transpose_conv<<<dim3(32, 32), 256, 0, stream>>>(Wo, WoT, DM, DM);

  // QKV projection: [8192,1024] x [1024,3072]
  gemm_k<0><<<dim3(24, 64), 256, 0, stream>>>(catB, WqkvT, DM, qwB, qrB, kBp, vBp, rwb, rrb);
  // R projection: [2048,1024] x [1024,1024]
  gemm_k<1><<<dim3(8, 16), 256, 0, stream>>>(rB, WrT, DM, rhB, nullptr, nullptr, nullptr, nullptr, nullptr);

  // fused attention (AC + sliding BD band + softmax + PV), all (b,h) at once
  attn_k<<<dim3(16, NH, BSZ), 256, 0, stream>>>(qwB, qrB, kBp, vBp, rhB, av);

  // output projection: [4096,1024] x [1024,1024]
  gemm_k<3><<<dim3(8, 32), 256, 0, stream>>>(av, WoT, DM, ao, nullptr, nullptr, nullptr, nullptr, nullptr);
  ln_k<<<dim3(4096), 256, 0, stream>>>(w, ao, gam, bet, out);
}

// Round 3
// 318.862 us; speedup vs baseline: 1.7709x; 1.1137x over previous
//
#include <hip/hip_runtime.h>
#include <hip/hip_bf16.h>
#include <stdint.h>

#define QLEN 1024
#define MLEN 1024
#define KLEN 2048
#define BSZ 4
#define NH 16
#define DH 64
#define DM 1024

typedef __attribute__((ext_vector_type(8))) short bf16x8;
typedef __attribute__((ext_vector_type(4))) float f32x4;
typedef unsigned short u16;
typedef unsigned int u32;

typedef unsigned int __attribute__((address_space(1))) gu32;
typedef unsigned int __attribute__((address_space(3))) lu32;

__device__ __forceinline__ void stage16(const void* g, void* l){
  __builtin_amdgcn_global_load_lds((const gu32*)g, (lu32*)l, 16, 0, 0);
}

__device__ __forceinline__ u16 f2b(float f){
  u32 u = __builtin_bit_cast(u32, f);
  u32 r = (u + 0x7FFFu + ((u >> 16) & 1u)) >> 16;
  return (u16)r;
}
__device__ __forceinline__ float b2f(u16 v){
  u32 u = ((u32)v) << 16;
  return __builtin_bit_cast(float, u);
}

// XOR swizzle for [rows][64]bf16 tiles (128B rows)
__device__ __forceinline__ int swz(int row, int byteoff){
  return (row << 7) + (byteoff ^ (((row ^ (row >> 3)) & 7) << 4));
}

// DPP 16-lane-row reductions (row_ror:N = 0x120+N). Steps 1,2,4,8 give a full
// 16-ring reduce; domain = lanes [16k,16k+15] = exactly the lanes holding one
// wave-row-group's S columns. VALU-only (no LDS pipe).
template<int C>
__device__ __forceinline__ float dppmax(float x){
  int t = __builtin_amdgcn_update_dpp(0, __builtin_bit_cast(int, x), C, 0xf, 0xf, true);
  return fmaxf(x, __builtin_bit_cast(float, t));
}
template<int C>
__device__ __forceinline__ float dppadd(float x){
  int t = __builtin_amdgcn_update_dpp(0, __builtin_bit_cast(int, x), C, 0xf, 0xf, true);
  return x + __builtin_bit_cast(float, t);
}

__device__ __forceinline__ void blk_barrier(){
  asm volatile("s_waitcnt lgkmcnt(0)" ::: "memory");
  __builtin_amdgcn_s_barrier();
  asm volatile("" ::: "memory");
}

// ---------------- conversion kernels ----------------

__global__ __launch_bounds__(256) void conv_cat(const float* __restrict__ mems,
                                                const float* __restrict__ w,
                                                u16* __restrict__ dst){
  int idx = blockIdx.x * 256 + threadIdx.x;
  const int memf4 = MLEN * BSZ * DM / 4;
  float4 v = (idx < memf4) ? ((const float4*)mems)[idx]
                           : ((const float4*)w)[idx - memf4];
  ushort4 o;
  o.x = f2b(v.x); o.y = f2b(v.y); o.z = f2b(v.z); o.w = f2b(v.w);
  ((ushort4*)dst)[idx] = o;
}

__global__ __launch_bounds__(256) void conv_r(const float* __restrict__ r,
                                              u16* __restrict__ dst){
  int idx = blockIdx.x * 256 + threadIdx.x;
  float4 v = ((const float4*)r)[idx];
  ushort4 o;
  o.x = f2b(v.x); o.y = f2b(v.y); o.z = f2b(v.z); o.w = f2b(v.w);
  ((ushort4*)dst)[idx] = o;
}

__global__ __launch_bounds__(256) void transpose_conv(const float* __restrict__ src,
                                                      u16* __restrict__ dst,
                                                      int R, int C){
  __shared__ float tile[32][33];
  int c0 = blockIdx.x * 32, r0 = blockIdx.y * 32;
  int tx = threadIdx.x & 31, ty = threadIdx.x >> 5;
  #pragma unroll
  for (int rr = ty; rr < 32; rr += 8)
    tile[rr][tx] = src[(size_t)(r0 + rr) * C + c0 + tx];
  __syncthreads();
  #pragma unroll
  for (int rr = ty; rr < 32; rr += 8)
    dst[(size_t)(c0 + rr) * R + r0 + tx] = f2b(tile[tx][rr]);
}

// ---------------- generic bf16 MFMA GEMM (128x128 tile, BK=32) ----------------
// MODE 0: QKV projection epilogue (writes q raw, k, v)
// MODE 1: R projection epilogue (writes rh in [h][t][d])
// MODE 3: plain f32 row-major C

template<int MODE>
__global__ __launch_bounds__(256, 2) void gemm_k(
    const u16* __restrict__ A, const u16* __restrict__ Bt, int K,
    void* __restrict__ o0, void* __restrict__ o1, void* __restrict__ o2)
{
  __shared__ u16 As[128 * 32];
  __shared__ u16 Bs[128 * 32];
  const int tid = threadIdx.x;
  const int lane = tid & 63, w = tid >> 6;
  const int wr = w >> 1, wc = w & 1;
  const int lr = lane >> 4, lc = lane & 15;
  const int m0 = blockIdx.y * 128, n0 = blockIdx.x * 128;

  f32x4 acc[4][4];
  #pragma unroll
  for (int i = 0; i < 4; i++)
    #pragma unroll
    for (int j = 0; j < 4; j++)
      acc[i][j] = (f32x4){0.f, 0.f, 0.f, 0.f};

  for (int k0 = 0; k0 < K; k0 += 32){
    #pragma unroll
    for (int rnd = 0; rnd < 2; rnd++){
      int c = rnd * 256 + w * 64 + lane;
      int row = c >> 2, kc = c & 3;
      stage16((const char*)A + ((size_t)(m0 + row) * K + k0 + kc * 8) * 2,
              (char*)As + (rnd * 256 + w * 64) * 16);
      stage16((const char*)Bt + ((size_t)(n0 + row) * K + k0 + kc * 8) * 2,
              (char*)Bs + (rnd * 256 + w * 64) * 16);
    }
    asm volatile("s_waitcnt vmcnt(0)");
    __syncthreads();

    bf16x8 af[4], bfr[4];
    #pragma unroll
    for (int mf = 0; mf < 4; mf++)
      af[mf] = *(const bf16x8*)((const char*)As + (wr * 64 + mf * 16 + lc) * 64 + lr * 16);
    #pragma unroll
    for (int nf = 0; nf < 4; nf++)
      bfr[nf] = *(const bf16x8*)((const char*)Bs + (wc * 64 + nf * 16 + lc) * 64 + lr * 16);
    #pragma unroll
    for (int mf = 0; mf < 4; mf++)
      #pragma unroll
      for (int nf = 0; nf < 4; nf++)
        acc[mf][nf] = __builtin_amdgcn_mfma_f32_16x16x32_bf16(af[mf], bfr[nf], acc[mf][nf], 0, 0, 0);
    __syncthreads();
  }

  #pragma unroll
  for (int mf = 0; mf < 4; mf++){
    #pragma unroll
    for (int nf = 0; nf < 4; nf++){
      #pragma unroll
      for (int e = 0; e < 4; e++){
        float v = acc[mf][nf][e];
        int row = m0 + wr * 64 + mf * 16 + lr * 4 + e;
        int col = n0 + wc * 64 + nf * 16 + lc;
        if constexpr (MODE == 0){
          int t = row >> 2, bb = row & 3;
          int s = col >> 10, rem = col & 1023;
          int h = rem >> 6, d = rem & 63;
          if (s == 0){
            if (t >= MLEN)
              ((u16*)o0)[((size_t)(bb * NH + h) * QLEN + (t - MLEN)) * DH + d] = f2b(v);
          } else {
            size_t oi = ((size_t)(bb * NH + h) * KLEN + t) * DH + d;
            if (s == 1) ((u16*)o1)[oi] = f2b(v);   // k
            else        ((u16*)o2)[oi] = f2b(v);   // v
          }
        } else if constexpr (MODE == 1){
          int h = col >> 6, d = col & 63;
          ((u16*)o0)[((size_t)h * KLEN + row) * DH + d] = f2b(v);
        } else {
          ((float*)o0)[(size_t)row * DM + col] = v;
        }
      }
    }
  }
}

// ---------------- fused flash attention, pipelined ----------------
// 4 waves x 16 q-rows = 64-row blocks. Double-buffered K/R (global_load_lds)
// and V (reg-staged), counted vmcnt(6), raw s_barrier (no vmem drain at
// barriers). BD band strips in bf16 LDS with lr-XOR column swizzle.
// Block remap: 16 i-blocks of one (b,h) land on one XCD for L2 reuse.

__global__ __launch_bounds__(256, 2) void attn_k(
    const u16* __restrict__ qB,  const u16* __restrict__ kB,
    const u16* __restrict__ vB,  const u16* __restrict__ rhB,
    const float* __restrict__ rwb, const float* __restrict__ rrb,
    u16* __restrict__ av)
{
  __shared__ u16 Kt[2][64 * 64];
  __shared__ u16 Vt[2][64 * 64];
  __shared__ u16 Rb[2][64 * 64];
  __shared__ u16 Pt[4][16 * 64];
  __shared__ u16 Pbd[4][2][16][72];   // bf16 BD strips, parity dbuf, lr-XOR cols

  const int tid = threadIdx.x, lane = tid & 63, w = tid >> 6;
  const int lr = lane >> 4, lc = lane & 15;

  // XCD-locality remap: consecutive hw bids round-robin XCDs; give each XCD
  // contiguous (b,h) groups with i fastest.
  const int bid = blockIdx.x;
  const int nid = (bid & 7) * 128 + (bid >> 3);
  const int i0 = (nid & 15) * 64;
  const int h  = (nid >> 4) & 15;
  const int b  = nid >> 8;
  const size_t bh = (size_t)b * NH + h;

  // Q fragments: load raw q once, add r_w_bias / r_r_bias here.
  bf16x8 qw_[2], qr_[2];
  #pragma unroll
  for (int ks = 0; ks < 2; ks++){
    bf16x8 qv = *(const bf16x8*)(qB + (bh * QLEN + i0 + w * 16 + lc) * DH + ks * 32 + lr * 8);
    #pragma unroll
    for (int e2 = 0; e2 < 8; e2++){
      int d = ks * 32 + lr * 8 + e2;
      float q32 = b2f((u16)qv[e2]);
      qw_[ks][e2] = (short)f2b(q32 + rwb[h * DH + d]);
      qr_[ks][e2] = (short)f2b(q32 + rrb[h * DH + d]);
    }
  }

  f32x4 O[4];
  float mx[4], sm[4];
  #pragma unroll
  for (int df = 0; df < 4; df++) O[df] = (f32x4){0.f, 0.f, 0.f, 0.f};
  #pragma unroll
  for (int e = 0; e < 4; e++){ mx[e] = -3.0e38f; sm[e] = 0.f; }

  const char* kgb = (const char*)(kB + bh * KLEN * DH);
  const char* vgb = (const char*)(vB + bh * KLEN * DH);
  const char* rgb = (const char*)(rhB + (size_t)h * KLEN * DH);

  const int jtiles = (i0 >> 6) + 17;
  bf16x8 vcur[2], vnext[2];

  // ---- prologue ----
  {
    int tb0 = 959 - i0;     // prev band start
    int tb1 = 1023 - i0;    // band for tile 0
    #pragma unroll
    for (int rnd = 0; rnd < 2; rnd++){
      int c = rnd * 256 + tid;
      int row = c >> 3;
      int ch = (c & 7) ^ ((row ^ (row >> 3)) & 7);
      int t = tb0 + row; t = t < 0 ? 0 : t;
      stage16(rgb + (size_t)t * 128 + ch * 16, (char*)&Rb[1][0] + c * 16);
    }
    #pragma unroll
    for (int rnd = 0; rnd < 2; rnd++){
      int c = rnd * 256 + tid;
      int row = c >> 3;
      int ch = (c & 7) ^ ((row ^ (row >> 3)) & 7);
      stage16(kgb + (size_t)row * 128 + ch * 16, (char*)&Kt[0][0] + c * 16);
    }
    #pragma unroll
    for (int rnd = 0; rnd < 2; rnd++){
      int c = rnd * 256 + tid;
      int row = c >> 3;
      int ch = (c & 7) ^ ((row ^ (row >> 3)) & 7);
      int t = tb1 + row;
      stage16(rgb + (size_t)t * 128 + ch * 16, (char*)&Rb[0][0] + c * 16);
    }
    #pragma unroll
    for (int rnd = 0; rnd < 2; rnd++){
      int c = rnd * 256 + tid;
      vcur[rnd] = *(const bf16x8*)(vgb + (size_t)c * 16);
    }
    asm volatile("s_waitcnt vmcnt(4)" ::: "memory");
    blk_barrier();
    // BD for prev band -> Pbd[.][1]
    #pragma unroll
    for (int n2 = 0; n2 < 4; n2++){
      bf16x8 r0 = *(const bf16x8*)((const char*)&Rb[1][0] + swz(n2 * 16 + lc, lr * 16));
      bf16x8 r1 = *(const bf16x8*)((const char*)&Rb[1][0] + swz(n2 * 16 + lc, 64 + lr * 16));
      f32x4 z = (f32x4){0.f, 0.f, 0.f, 0.f};
      z = __builtin_amdgcn_mfma_f32_16x16x32_bf16(qr_[0], r0, z, 0, 0, 0);
      z = __builtin_amdgcn_mfma_f32_16x16x32_bf16(qr_[1], r1, z, 0, 0, 0);
      #pragma unroll
      for (int e = 0; e < 4; e++)
        Pbd[w][1][lr * 4 + e][(n2 * 16 + lc) ^ (lr << 4)] = f2b(z[e]);
    }
    blk_barrier();
  }

  for (int jt = 0; jt < jtiles; jt++){
    const int j0 = jt * 64;
    const int cur = jt & 1, nxt = cur ^ 1;
    const bool lastT = (jt == jtiles - 1);

    // ---- issue next-tile stages (stay in flight across barriers) ----
    {
      int jn = (jt + 1 < jtiles ? jt + 1 : jtiles - 1) * 64;
      int tbn = 1023 - i0 + (jt + 1) * 64;
      #pragma unroll
      for (int rnd = 0; rnd < 2; rnd++){
        int c = rnd * 256 + tid;
        int row = c >> 3;
        int ch = (c & 7) ^ ((row ^ (row >> 3)) & 7);
        stage16(kgb + (size_t)(jn + row) * 128 + ch * 16, (char*)&Kt[nxt][0] + c * 16);
      }
      #pragma unroll
      for (int rnd = 0; rnd < 2; rnd++){
        int c = rnd * 256 + tid;
        int row = c >> 3;
        int ch = (c & 7) ^ ((row ^ (row >> 3)) & 7);
        int t = tbn + row; t = t > 2047 ? 2047 : t;
        stage16(rgb + (size_t)t * 128 + ch * 16, (char*)&Rb[nxt][0] + c * 16);
      }
      #pragma unroll
      for (int rnd = 0; rnd < 2; rnd++){
        int c = rnd * 256 + tid;
        vnext[rnd] = *(const bf16x8*)(vgb + (size_t)jn * 128 + c * 16);
      }
    }
    asm volatile("s_waitcnt vmcnt(6)" ::: "memory");

    // scatter current V (regs) -> Vt[cur], swizzled
    #pragma unroll
    for (int rnd = 0; rnd < 2; rnd++){
      int c = rnd * 256 + tid;
      int j = c >> 3, d0 = (c & 7) * 8;
      #pragma unroll
      for (int e2 = 0; e2 < 8; e2++)
        *(u16*)((char*)&Vt[cur][0] + swz(d0 + e2, j * 2)) = (u16)vcur[rnd][e2];
    }
    blk_barrier();   // BARRIER A: Kt/Rb[cur] (vmcnt'd) + Vt[cur] visible

    // ---- AC = (q+rwb) K^T ----
    f32x4 s[4];
    __builtin_amdgcn_s_setprio(1);
    #pragma unroll
    for (int n = 0; n < 4; n++){
      bf16x8 k0f = *(const bf16x8*)((const char*)&Kt[cur][0] + swz(n * 16 + lc, lr * 16));
      bf16x8 k1f = *(const bf16x8*)((const char*)&Kt[cur][0] + swz(n * 16 + lc, 64 + lr * 16));
      f32x4 z = (f32x4){0.f, 0.f, 0.f, 0.f};
      z = __builtin_amdgcn_mfma_f32_16x16x32_bf16(qw_[0], k0f, z, 0, 0, 0);
      z = __builtin_amdgcn_mfma_f32_16x16x32_bf16(qw_[1], k1f, z, 0, 0, 0);
      s[n] = z;
    }
    // ---- BD band -> Pbd[cur] ----
    #pragma unroll
    for (int n2 = 0; n2 < 4; n2++){
      bf16x8 r0 = *(const bf16x8*)((const char*)&Rb[cur][0] + swz(n2 * 16 + lc, lr * 16));
      bf16x8 r1 = *(const bf16x8*)((const char*)&Rb[cur][0] + swz(n2 * 16 + lc, 64 + lr * 16));
      f32x4 z = (f32x4){0.f, 0.f, 0.f, 0.f};
      z = __builtin_amdgcn_mfma_f32_16x16x32_bf16(qr_[0], r0, z, 0, 0, 0);
      z = __builtin_amdgcn_mfma_f32_16x16x32_bf16(qr_[1], r1, z, 0, 0, 0);
      #pragma unroll
      for (int e = 0; e < 4; e++)
        Pbd[w][cur][lr * 4 + e][(n2 * 16 + lc) ^ (lr << 4)] = f2b(z[e]);
    }
    __builtin_amdgcn_s_setprio(0);
    asm volatile("s_waitcnt lgkmcnt(0)" ::: "memory");

    // ---- softmax (DPP 16-lane reductions, no LDS shuffles) ----
    float p[4][4];
    float fac[4];
    #pragma unroll
    for (int e = 0; e < 4; e++){
      int r = lr * 4 + e;
      int il = w * 16 + r;
      int i = i0 + il;
      float sv[4];
      float tm = -3.0e38f;
      #pragma unroll
      for (int n = 0; n < 4; n++){
        int jl = n * 16 + lc;
        int dd = jl - il;
        u16 bd = Pbd[w][dd >= 0 ? cur : nxt][r][(dd & 63) ^ (lr << 4)];
        float x = (s[n][e] + b2f(bd)) * 0.125f;
        if (lastT && (j0 + jl > i + MLEN)) x = -1.0e30f;
        sv[n] = x;
        tm = fmaxf(tm, x);
      }
      tm = dppmax<0x121>(tm); tm = dppmax<0x122>(tm);
      tm = dppmax<0x124>(tm); tm = dppmax<0x128>(tm);
      float nm = fmaxf(mx[e], tm);
      float fc = __expf(mx[e] - nm);
      mx[e] = nm;
      float ps = 0.f;
      #pragma unroll
      for (int n = 0; n < 4; n++){
        float pv = __expf(sv[n] - nm);
        p[n][e] = pv;
        ps += pv;
      }
      ps = dppadd<0x121>(ps); ps = dppadd<0x122>(ps);
      ps = dppadd<0x124>(ps); ps = dppadd<0x128>(ps);
      sm[e] = sm[e] * fc + ps;
      fac[e] = fc;
    }
    #pragma unroll
    for (int df = 0; df < 4; df++)
      #pragma unroll
      for (int e = 0; e < 4; e++)
        O[df][e] *= fac[e];
    #pragma unroll
    for (int n = 0; n < 4; n++)
      #pragma unroll
      for (int e = 0; e < 4; e++)
        *(u16*)((char*)&Pt[w][0] + swz(lr * 4 + e, (n * 16 + lc) * 2)) = f2b(p[n][e]);

    asm volatile("s_waitcnt lgkmcnt(0)" ::: "memory");

    // ---- O += P @ V ----
    bf16x8 pa0 = *(const bf16x8*)((const char*)&Pt[w][0] + swz(lc, lr * 16));
    bf16x8 pa1 = *(const bf16x8*)((const char*)&Pt[w][0] + swz(lc, 64 + lr * 16));
    __builtin_amdgcn_s_setprio(1);
    #pragma unroll
    for (int df = 0; df < 4; df++){
      bf16x8 v0 = *(const bf16x8*)((const char*)&Vt[cur][0] + swz(df * 16 + lc, lr * 16));
      bf16x8 v1 = *(const bf16x8*)((const char*)&Vt[cur][0] + swz(df * 16 + lc, 64 + lr * 16));
      O[df] = __builtin_amdgcn_mfma_f32_16x16x32_bf16(pa0, v0, O[df], 0, 0, 0);
      O[df] = __builtin_amdgcn_mfma_f32_16x16x32_bf16(pa1, v1, O[df], 0, 0, 0);
    }
    __builtin_amdgcn_s_setprio(0);
    blk_barrier();   // BARRIER B: all reads of [cur] done before re-stage
    vcur[0] = vnext[0]; vcur[1] = vnext[1];
  }

  #pragma unroll
  for (int df = 0; df < 4; df++)
    #pragma unroll
    for (int e = 0; e < 4; e++){
      int i = i0 + w * 16 + lr * 4 + e;
      av[(size_t)(i * BSZ + b) * DM + h * DH + df * 16 + lc] = f2b(O[df][e] / sm[e]);
    }
}

// ---------------- residual + LayerNorm ----------------

__global__ __launch_bounds__(256) void ln_k(const float* __restrict__ w,
                                            const float* __restrict__ ao,
                                            const float* __restrict__ gam,
                                            const float* __restrict__ bet,
                                            float* __restrict__ out){
  __shared__ float red[8];
  const int rw = blockIdx.x, t = threadIdx.x, lane = t & 63, wv = t >> 6;
  const float* wr_ = w + (size_t)rw * DM;
  const float* ar_ = ao + (size_t)rw * DM;
  float x[4];
  float s = 0.f, ss = 0.f;
  #pragma unroll
  for (int k2 = 0; k2 < 4; k2++){
    int c = t + k2 * 256;
    float xv = wr_[c] + ar_[c];
    x[k2] = xv; s += xv; ss += xv * xv;
  }
  #pragma unroll
  for (int m2 = 1; m2 < 64; m2 <<= 1){ s += __shfl_xor(s, m2); ss += __shfl_xor(ss, m2); }
  if (lane == 0){ red[wv] = s; red[4 + wv] = ss; }
  __syncthreads();
  s  = red[0] + red[1] + red[2] + red[3];
  ss = red[4] + red[5] + red[6] + red[7];
  float mu = s * (1.f / DM);
  float var = ss * (1.f / DM) - mu * mu;
  float rs = rsqrtf(var + 1e-5f);
  #pragma unroll
  for (int k2 = 0; k2 < 4; k2++){
    int c = t + k2 * 256;
    out[(size_t)rw * DM + c] = (x[k2] - mu) * rs * gam[c] + bet[c];
  }
}

// ---------------- launch ----------------

extern "C" void kernel_launch(void* const* d_in, const int* in_sizes, int n_in,
                              void* d_out, int out_size, void* d_ws, size_t ws_size,
                              hipStream_t stream)
{
  (void)in_sizes; (void)n_in; (void)out_size; (void)ws_size;
  const float* w    = (const float*)d_in[0];
  const float* r    = (const float*)d_in[1];
  const float* mems = (const float*)d_in[2];
  const float* Wqkv = (const float*)d_in[3];
  const float* Wr   = (const float*)d_in[4];
  const float* Wo   = (const float*)d_in[5];
  const float* rwb  = (const float*)d_in[6];
  const float* rrb  = (const float*)d_in[7];
  const float* gam  = (const float*)d_in[8];
  const float* bet  = (const float*)d_in[9];
  float* out = (float*)d_out;

  char* ws = (char*)d_ws;
  size_t off = 0;
  auto alloc = [&](size_t n){ char* p = ws + off; off += (n + 255) & ~(size_t)255; return p; };
  u16* catB  = (u16*)alloc((size_t)KLEN * BSZ * DM * 2);
  u16* rB    = (u16*)alloc((size_t)KLEN * DM * 2);
  u16* WqkvT = (u16*)alloc((size_t)3 * DM * DM * 2);
  u16* WrT   = (u16*)alloc((size_t)DM * DM * 2);
  u16* WoT   = (u16*)alloc((size_t)DM * DM * 2);
  u16* qBuf  = (u16*)alloc((size_t)BSZ * NH * QLEN * DH * 2);
  u16* kBp   = (u16*)alloc((size_t)BSZ * NH * KLEN * DH * 2);
  u16* vBp   = (u16*)alloc((size_t)BSZ * NH * KLEN * DH * 2);
  u16* rhB   = (u16*)alloc((size_t)NH * KLEN * DH * 2);
  u16* av    = (u16*)alloc((size_t)QLEN * BSZ * DM * 2);
  float* ao  = (float*)alloc((size_t)QLEN * BSZ * DM * 4);

  conv_cat<<<dim3(8192), 256, 0, stream>>>(mems, w, catB);
  conv_r<<<dim3(2048), 256, 0, stream>>>(r, rB);
  transpose_conv<<<dim3(96, 32), 256, 0, stream>>>(Wqkv, WqkvT, DM, 3 * DM);
  transpose_conv<<<dim3(32, 32), 256, 0, stream>>>(Wr, WrT, DM, DM);
  transpose_conv<<<dim3(32, 32), 256, 0, stream>>>(Wo, WoT, DM, DM);

  // QKV projection: [8192,1024] x [1024,3072]
  gemm_k<0><<<dim3(24, 64), 256, 0, stream>>>(catB, WqkvT, DM, qBuf, kBp, vBp);
  // R projection: [2048,1024] x [1024,1024]
  gemm_k<1><<<dim3(8, 16), 256, 0, stream>>>(rB, WrT, DM, rhB, nullptr, nullptr);

  // fused attention (AC + sliding BD band + softmax + PV), all (b,h,i) at once
  attn_k<<<dim3(1024), 256, 0, stream>>>(qBuf, kBp, vBp, rhB, rwb, rrb, av);

  // output projection: [4096,1024] x [1024,1024]
  gemm_k<3><<<dim3(8, 32), 256, 0, stream>>>(av, WoT, DM, ao, nullptr, nullptr);
  ln_k<<<dim3(4096), 256, 0, stream>>>(w, ao, gam, bet, out);
}